// Round 6
// baseline (552.749 us; speedup 1.0000x reference)
//
#include <hip/hip_runtime.h>

// BooleanREWAHead on MI355X (gfx950).
// Pipeline: prep_weights -> proj (MFMA, bf16 hi/lo 3-pass split, near-zero
// flagging) -> fixup (f64 recompute of flagged borderline signs) ->
// attn (exact bf16 score MFMA + direct exp + PV) -> normalize (attn /= rowsum).
// ws layout (~23.6 MB): WqhT,WqlT,WkhT,WklT [256][1024]bf16, WvhT [128][1024]bf16,
// Sq,Sk [16384][256]bf16(+-1), VpT [8*128][2048]bf16, rowsum [16384]f32,
// flag_count i32, flags[32768] i32.

typedef __attribute__((ext_vector_type(4))) float f32x4;
typedef __attribute__((ext_vector_type(8))) __bf16 bf16x8;

#define FLAG_CAP 32768
#define FLAG_TAU 2e-4f   // 50 sigma of 3-pass split error (sigma ~4e-6)

__device__ inline unsigned short f2b(float x) {  // f32 -> bf16 bits, RTNE
    unsigned int u = __float_as_uint(x);
    return (unsigned short)((u + 0x7FFFu + ((u >> 16) & 1u)) >> 16);
}

// ---------------- weight split+transpose ----------------
__global__ __launch_bounds__(256) void prep_weights(
    const float* __restrict__ Wq, const float* __restrict__ Wk, const float* __restrict__ Wv,
    unsigned short* __restrict__ WqhT, unsigned short* __restrict__ WqlT,
    unsigned short* __restrict__ WkhT, unsigned short* __restrict__ WklT,
    unsigned short* __restrict__ WvhT, int* __restrict__ flag_count)
{
    if (blockIdx.x == 0 && threadIdx.x == 0) *flag_count = 0;  // visible to next kernel
    int i = blockIdx.x * 256 + threadIdx.x;  // [0, 655360)
    const float* src; unsigned short *dh, *dl; int cols, j;
    if (i < 262144)      { src = Wq; dh = WqhT; dl = WqlT; cols = 256; j = i; }
    else if (i < 524288) { src = Wk; dh = WkhT; dl = WklT; cols = 256; j = i - 262144; }
    else                 { src = Wv; dh = WvhT; dl = nullptr; cols = 128; j = i - 524288; }
    int d = j / cols, m = j % cols;
    float x = src[j];
    unsigned short h = f2b(x);
    dh[(size_t)m * 1024 + d] = h;
    if (dl) {
        float hf = __uint_as_float(((unsigned int)h) << 16);
        dl[(size_t)m * 1024 + d] = f2b(x - hf);
    }
}

// ---------------- projection GEMM ----------------
// grid (256, 2, 3): z=0 Q->Sq, z=1 K->Sk (3-pass split, BN=128 via y), z=2 V->VpT (1-pass, y==0 only)
__global__ __launch_bounds__(256) void proj_kernel(
    const float* __restrict__ Q, const float* __restrict__ K, const float* __restrict__ V,
    const unsigned short* __restrict__ WqhT, const unsigned short* __restrict__ WqlT,
    const unsigned short* __restrict__ WkhT, const unsigned short* __restrict__ WklT,
    const unsigned short* __restrict__ WvhT,
    unsigned short* __restrict__ Sq, unsigned short* __restrict__ Sk,
    unsigned short* __restrict__ VpT,
    int* __restrict__ flag_count, int* __restrict__ flags)
{
    const int z = blockIdx.z, y = blockIdx.y;
    if (z == 2 && y == 1) return;
    const int m0 = blockIdx.x * 64;
    const bool split = (z < 2);
    const int n0 = split ? y * 128 : 0;
    const float* src = (z == 0) ? Q : (z == 1) ? K : V;
    const unsigned short* BhT = (z == 0) ? WqhT : (z == 1) ? WkhT : WvhT;
    const unsigned short* BlT = (z == 0) ? WqlT : WklT;

    __shared__ __align__(16) unsigned short smem[15360];
    unsigned short* Ah = smem;          // [64][40]
    unsigned short* Al = smem + 2560;   // [64][40]
    unsigned short* Bh = smem + 5120;   // [128][40]
    unsigned short* Bl = smem + 10240;  // [128][40]

    const int tid = threadIdx.x;
    const int wid = tid >> 6, lane = tid & 63;
    const int lr = lane & 15, lg = lane >> 4;

    f32x4 acc[8];
    #pragma unroll
    for (int t = 0; t < 8; ++t) acc[t] = f32x4{0.f, 0.f, 0.f, 0.f};

    for (int ks = 0; ks < 32; ++ks) {
        const int k0 = ks * 32;
        __syncthreads();
        {   // stage A: 64x32 fp32 -> bf16 hi/lo
            const int row = tid >> 2, quad = tid & 3;
            const float* p = src + (size_t)(m0 + row) * 1024 + k0 + quad * 8;
            float4 v0 = *(const float4*)p;
            float4 v1 = *(const float4*)(p + 4);
            float xs[8] = {v0.x, v0.y, v0.z, v0.w, v1.x, v1.y, v1.z, v1.w};
            unsigned short hs[8], ls[8];
            #pragma unroll
            for (int i = 0; i < 8; ++i) {
                unsigned short h = f2b(xs[i]);
                float hf = __uint_as_float(((unsigned int)h) << 16);
                hs[i] = h;
                ls[i] = f2b(xs[i] - hf);
            }
            *(uint4*)(Ah + row * 40 + quad * 8) = *(const uint4*)hs;
            if (split) *(uint4*)(Al + row * 40 + quad * 8) = *(const uint4*)ls;
        }
        {   // stage B: 128x32 bf16 from transposed weights
            const int row = tid >> 1, half = tid & 1;
            const unsigned short* ph = BhT + (size_t)(n0 + row) * 1024 + k0 + half * 16;
            uint4 b0 = *(const uint4*)ph;
            uint4 b1 = *(const uint4*)(ph + 8);
            *(uint4*)(Bh + row * 40 + half * 16) = b0;
            *(uint4*)(Bh + row * 40 + half * 16 + 8) = b1;
            if (split) {
                const unsigned short* pl = BlT + (size_t)(n0 + row) * 1024 + k0 + half * 16;
                uint4 c0 = *(const uint4*)pl;
                uint4 c1 = *(const uint4*)(pl + 8);
                *(uint4*)(Bl + row * 40 + half * 16) = c0;
                *(uint4*)(Bl + row * 40 + half * 16 + 8) = c1;
            }
        }
        __syncthreads();
        const bf16x8 a_h = *(const bf16x8*)(Ah + (wid * 16 + lr) * 40 + lg * 8);
        bf16x8 a_l;
        if (split) a_l = *(const bf16x8*)(Al + (wid * 16 + lr) * 40 + lg * 8);
        #pragma unroll
        for (int t = 0; t < 8; ++t) {
            const bf16x8 b_h = *(const bf16x8*)(Bh + (t * 16 + lr) * 40 + lg * 8);
            acc[t] = __builtin_amdgcn_mfma_f32_16x16x32_bf16(a_h, b_h, acc[t], 0, 0, 0);
            if (split) {
                const bf16x8 b_l = *(const bf16x8*)(Bl + (t * 16 + lr) * 40 + lg * 8);
                acc[t] = __builtin_amdgcn_mfma_f32_16x16x32_bf16(a_h, b_l, acc[t], 0, 0, 0);
                acc[t] = __builtin_amdgcn_mfma_f32_16x16x32_bf16(a_l, b_h, acc[t], 0, 0, 0);
            }
        }
    }

    if (z < 2) {  // sign epilogue: +-1.0 bf16, flag near-zero for f64 fixup
        unsigned short* dst = (z == 0) ? Sq : Sk;
        const int whichbit = z << 22;
        #pragma unroll
        for (int t = 0; t < 8; ++t)
            #pragma unroll
            for (int j = 0; j < 4; ++j) {
                const int row = m0 + wid * 16 + 4 * lg + j;
                const int col = n0 + t * 16 + lr;
                const float zv = acc[t][j];
                dst[(size_t)row * 256 + col] =
                    (zv > 0.f) ? (unsigned short)0x3F80 : (unsigned short)0xBF80;
                if (__builtin_fabsf(zv) < FLAG_TAU) {
                    int slot = atomicAdd(flag_count, 1);
                    if (slot < FLAG_CAP) flags[slot] = whichbit | (row << 8) | col;
                }
            }
    } else {      // Vp -> VpT[b][h][key] bf16 via LDS transpose
        __syncthreads();
        unsigned short* tp = smem;  // [128][72]
        #pragma unroll
        for (int t = 0; t < 8; ++t)
            #pragma unroll
            for (int j = 0; j < 4; ++j) {
                const int h = t * 16 + lr;
                const int key = wid * 16 + 4 * lg + j;
                tp[h * 72 + key] = f2b(acc[t][j]);
            }
        __syncthreads();
        const int b = m0 >> 11, key0 = m0 & 2047;
        const int h = tid >> 1, half = tid & 1;
        const unsigned short* sp = tp + h * 72 + half * 32;
        unsigned short* gp = VpT + (size_t)(b * 128 + h) * 2048 + key0 + half * 32;
        #pragma unroll
        for (int i = 0; i < 4; ++i)
            *(uint4*)(gp + i * 8) = *(const uint4*)(sp + i * 8);
    }
}

// ---------------- f64 sign fixup of flagged borderline projections ----------------
__global__ __launch_bounds__(256) void fixup_kernel(
    const float* __restrict__ Q, const float* __restrict__ K,
    const float* __restrict__ Wq, const float* __restrict__ Wk,
    unsigned short* __restrict__ Sq, unsigned short* __restrict__ Sk,
    const int* __restrict__ flag_count, const int* __restrict__ flags)
{
    const int nflags = min(*flag_count, FLAG_CAP);
    const int wave = (int)(blockIdx.x * 256 + threadIdx.x) >> 6;
    const int lane = threadIdx.x & 63;
    const int nwaves = gridDim.x * 4;
    for (int i = wave; i < nflags; i += nwaves) {
        const int enc = flags[i];
        const int which = enc >> 22;
        const int row = (enc >> 8) & 0x3FFF;   // b*2048+n
        const int col = enc & 255;             // m
        const float* srow = (which ? K : Q) + (size_t)row * 1024;
        const float* W = (which ? Wk : Wq) + col;
        double accd = 0.0;
        #pragma unroll 4
        for (int d = lane; d < 1024; d += 64)
            accd += (double)srow[d] * (double)W[(size_t)d * 256];
        #pragma unroll
        for (int off = 32; off; off >>= 1) accd += __shfl_xor(accd, off);
        if (lane == 0)
            (which ? Sk : Sq)[(size_t)row * 256 + col] =
                (accd > 0.0) ? (unsigned short)0x3F80 : (unsigned short)0xBF80;
    }
}

// ---------------- attention ----------------
// grid (32, 8): 64 queries/block, 4 waves (16 q each), 64 key-tiles of 32.
__global__ __launch_bounds__(256) void attn_kernel(
    const unsigned short* __restrict__ Sq, const unsigned short* __restrict__ Sk,
    const unsigned short* __restrict__ VpT,
    float* __restrict__ attn, float* __restrict__ out, float* __restrict__ rowsum)
{
    const int b = blockIdx.y;
    const int q0 = blockIdx.x * 64;
    const int tid = threadIdx.x;
    const int wid = tid >> 6, lane = tid & 63;
    const int lr = lane & 15, lg = lane >> 4;

    __shared__ __align__(16) unsigned short sk_lds[32][264];
    __shared__ __align__(16) unsigned short vpt_lds[128][40];
    __shared__ __align__(16) unsigned short e_lds[4][16][40];

    uint4 sqf[8];  // wave-persistent sq fragments (q rows: wid*16+lr, all 256 mbits)
    {
        const unsigned short* p =
            Sq + (size_t)(b * 2048 + q0 + wid * 16 + lr) * 256 + lg * 8;
        #pragma unroll
        for (int s = 0; s < 8; ++s) sqf[s] = *(const uint4*)(p + s * 32);
    }

    f32x4 oacc[8];
    #pragma unroll
    for (int t = 0; t < 8; ++t) oacc[t] = f32x4{0.f, 0.f, 0.f, 0.f};
    float racc[4] = {0.f, 0.f, 0.f, 0.f};

    float* attn_row_base = attn + (size_t)(b * 2048 + q0 + wid * 16 + 4 * lg) * 2048;

    for (int kt = 0; kt < 64; ++kt) {
        const int kt0 = kt * 32;
        __syncthreads();
        {   // stage sk: 32 keys x 256 mbits
            const int row = tid >> 3, chunk = tid & 7;
            const unsigned short* p = Sk + (size_t)(b * 2048 + kt0 + row) * 256 + chunk * 32;
            uint4 v0 = *(const uint4*)(p);
            uint4 v1 = *(const uint4*)(p + 8);
            uint4 v2 = *(const uint4*)(p + 16);
            uint4 v3 = *(const uint4*)(p + 24);
            unsigned short* q = &sk_lds[row][chunk * 32];
            *(uint4*)(q) = v0; *(uint4*)(q + 8) = v1;
            *(uint4*)(q + 16) = v2; *(uint4*)(q + 24) = v3;
        }
        {   // stage VpT: 128 h x 32 keys
            const int h = tid >> 1, half = tid & 1;
            const unsigned short* p = VpT + (size_t)(b * 128 + h) * 2048 + kt0 + half * 16;
            uint4 v0 = *(const uint4*)(p);
            uint4 v1 = *(const uint4*)(p + 8);
            unsigned short* q = &vpt_lds[h][half * 16];
            *(uint4*)(q) = v0; *(uint4*)(q + 8) = v1;
        }
        __syncthreads();

        // exact score MFMA: dot[q 16][key 32]
        f32x4 dacc[2];
        dacc[0] = f32x4{0.f, 0.f, 0.f, 0.f};
        dacc[1] = f32x4{0.f, 0.f, 0.f, 0.f};
        #pragma unroll
        for (int s = 0; s < 8; ++s) {
            const bf16x8 a = *(const bf16x8*)(&sqf[s]);
            #pragma unroll
            for (int t2 = 0; t2 < 2; ++t2) {
                const bf16x8 bk = *(const bf16x8*)(&sk_lds[t2 * 16 + lr][s * 32 + lg * 8]);
                dacc[t2] = __builtin_amdgcn_mfma_f32_16x16x32_bf16(a, bk, dacc[t2], 0, 0, 0);
            }
        }
        // e = exp(score) (no max needed: score <= 16), store unnormalized, stage for PV
        #pragma unroll
        for (int t2 = 0; t2 < 2; ++t2)
            #pragma unroll
            for (int j = 0; j < 4; ++j) {
                float e = __expf((dacc[t2][j] + 256.0f) * 0.03125f);
                racc[j] += e;
                attn_row_base[(size_t)j * 2048 + kt0 + t2 * 16 + lr] = e;
                e_lds[wid][4 * lg + j][t2 * 16 + lr] = f2b(e);
            }
        // PV MFMA: out[q 16][h 128] += e[q][key 32] * Vp[key][h]
        const bf16x8 ea = *(const bf16x8*)(&e_lds[wid][lr][lg * 8]);
        #pragma unroll
        for (int t = 0; t < 8; ++t) {
            const bf16x8 vb = *(const bf16x8*)(&vpt_lds[t * 16 + lr][lg * 8]);
            oacc[t] = __builtin_amdgcn_mfma_f32_16x16x32_bf16(ea, vb, oacc[t], 0, 0, 0);
        }
    }

    // rowsum: reduce over the 16 lanes of each lane-group
    #pragma unroll
    for (int j = 0; j < 4; ++j) {
        float v = racc[j];
        v += __shfl_xor(v, 1);
        v += __shfl_xor(v, 2);
        v += __shfl_xor(v, 4);
        v += __shfl_xor(v, 8);
        racc[j] = v;
    }
    if (lr == 0) {
        #pragma unroll
        for (int j = 0; j < 4; ++j)
            rowsum[b * 2048 + q0 + wid * 16 + 4 * lg + j] = racc[j];
    }
    #pragma unroll
    for (int t = 0; t < 8; ++t)
        #pragma unroll
        for (int j = 0; j < 4; ++j)
            out[(size_t)(b * 2048 + q0 + wid * 16 + 4 * lg + j) * 128 + t * 16 + lr] =
                oacc[t][j] / racc[j];
}

// ---------------- attn normalization ----------------
__global__ __launch_bounds__(256) void normalize_kernel(
    float* __restrict__ attn, const float* __restrict__ rowsum)
{
    const size_t idx4 = (size_t)blockIdx.x * 256 + threadIdx.x;  // float4 index
    const int row = (int)(idx4 >> 9);                            // 512 float4 per row
    const float inv = 1.0f / rowsum[row];
    float4* p = (float4*)attn + idx4;
    float4 v = *p;
    v.x *= inv; v.y *= inv; v.z *= inv; v.w *= inv;
    *p = v;
}

extern "C" void kernel_launch(void* const* d_in, const int* in_sizes, int n_in,
                              void* d_out, int out_size, void* d_ws, size_t ws_size,
                              hipStream_t stream)
{
    const float* Q  = (const float*)d_in[0];
    const float* K  = (const float*)d_in[1];
    const float* V  = (const float*)d_in[2];
    const float* Wq = (const float*)d_in[3];
    const float* Wk = (const float*)d_in[4];
    const float* Wv = (const float*)d_in[5];

    unsigned short* ws   = (unsigned short*)d_ws;
    unsigned short* WqhT = ws;
    unsigned short* WqlT = WqhT + 262144;
    unsigned short* WkhT = WqlT + 262144;
    unsigned short* WklT = WkhT + 262144;
    unsigned short* WvhT = WklT + 262144;
    unsigned short* Sq   = WvhT + 131072;
    unsigned short* Sk   = Sq + 4194304;
    unsigned short* VpT  = Sk + 4194304;
    float* rowsum    = (float*)(VpT + 2097152);
    int* flag_count  = (int*)(rowsum + 16384);
    int* flags       = flag_count + 1;

    float* out  = (float*)d_out;
    float* attn = out + 2097152;  // 8*2048*128

    prep_weights<<<2560, 256, 0, stream>>>(Wq, Wk, Wv, WqhT, WqlT, WkhT, WklT, WvhT,
                                           flag_count);
    proj_kernel<<<dim3(256, 2, 3), 256, 0, stream>>>(Q, K, V, WqhT, WqlT, WkhT, WklT, WvhT,
                                                     Sq, Sk, VpT, flag_count, flags);
    fixup_kernel<<<64, 256, 0, stream>>>(Q, K, Wq, Wk, Sq, Sk, flag_count, flags);
    attn_kernel<<<dim3(32, 8), 256, 0, stream>>>(Sq, Sk, VpT, attn, out, rowsum);
    normalize_kernel<<<32768, 256, 0, stream>>>(attn, rowsum);
}

// Round 10
// 482.529 us; speedup vs baseline: 1.1455x; 1.1455x over previous
//
#include <hip/hip_runtime.h>

// BooleanREWAHead on MI355X (gfx950). R9: proj reg-staged 2-phase pipeline +
// cvt_pk bf16 split; attn key-split x{4,2,1} ADAPTIVE to ws_size (R8's fixed
// 57MB layout is the suspected container-killer if ws_size < 57MB).
// ws layout (fixed part ~22.4 MB): WqhT,WqlT,WkhT,WklT [256][1024]bf16,
// WvhT [128][1024]bf16, Sq,Sk [16384][256]bf16, VpT [8*128][2048]bf16,
// flag_count i32, flags[32768] i32, then rowsum_part [ns][16384]f32,
// out_part [ns][16384][128]f32 (only if ns>1).

typedef __attribute__((ext_vector_type(4))) float f32x4;
typedef __attribute__((ext_vector_type(8))) __bf16 bf16x8;

#define FLAG_CAP 32768
#define FLAG_TAU 2e-4f   // 50 sigma of 3-pass split error (sigma ~4e-6)

__device__ inline unsigned short f2b(float x) {  // f32 -> bf16 bits, RTNE
    unsigned int u = __float_as_uint(x);
    return (unsigned short)((u + 0x7FFFu + ((u >> 16) & 1u)) >> 16);
}

// ---------------- weight split+transpose ----------------
__global__ __launch_bounds__(256) void prep_weights(
    const float* __restrict__ Wq, const float* __restrict__ Wk, const float* __restrict__ Wv,
    unsigned short* __restrict__ WqhT, unsigned short* __restrict__ WqlT,
    unsigned short* __restrict__ WkhT, unsigned short* __restrict__ WklT,
    unsigned short* __restrict__ WvhT, int* __restrict__ flag_count)
{
    if (blockIdx.x == 0 && threadIdx.x == 0) *flag_count = 0;  // visible to next kernel
    int i = blockIdx.x * 256 + threadIdx.x;  // [0, 655360)
    const float* src; unsigned short *dh, *dl; int cols, j;
    if (i < 262144)      { src = Wq; dh = WqhT; dl = WqlT; cols = 256; j = i; }
    else if (i < 524288) { src = Wk; dh = WkhT; dl = WklT; cols = 256; j = i - 262144; }
    else                 { src = Wv; dh = WvhT; dl = nullptr; cols = 128; j = i - 524288; }
    int d = j / cols, m = j % cols;
    float x = src[j];
    unsigned short h = f2b(x);
    dh[(size_t)m * 1024 + d] = h;
    if (dl) {
        float hf = __uint_as_float(((unsigned int)h) << 16);
        dl[(size_t)m * 1024 + d] = f2b(x - hf);
    }
}

// ---------------- projection GEMM (2-phase reg-staged pipeline) ----------------
// grid (256, 2, 3): z=0 Q->Sq, z=1 K->Sk (3-pass split, BN=128 via y), z=2 V->VpT (y==0 only)
__global__ __launch_bounds__(256) void proj_kernel(
    const float* __restrict__ Q, const float* __restrict__ K, const float* __restrict__ V,
    const unsigned short* __restrict__ WqhT, const unsigned short* __restrict__ WqlT,
    const unsigned short* __restrict__ WkhT, const unsigned short* __restrict__ WklT,
    const unsigned short* __restrict__ WvhT,
    unsigned short* __restrict__ Sq, unsigned short* __restrict__ Sk,
    unsigned short* __restrict__ VpT,
    int* __restrict__ flag_count, int* __restrict__ flags)
{
    const int z = blockIdx.z, y = blockIdx.y;
    if (z == 2 && y == 1) return;
    const int m0 = blockIdx.x * 64;
    const bool split = (z < 2);
    const int n0 = split ? y * 128 : 0;
    const float* src = (z == 0) ? Q : (z == 1) ? K : V;
    const unsigned short* BhT = (z == 0) ? WqhT : (z == 1) ? WkhT : WvhT;
    const unsigned short* BlT = (z == 0) ? WqlT : WklT;

    __shared__ __align__(16) unsigned short smem[15360];
    unsigned short* Ah = smem;          // [64][40]
    unsigned short* Al = smem + 2560;   // [64][40]
    unsigned short* Bh = smem + 5120;   // [128][40]
    unsigned short* Bl = smem + 10240;  // [128][40]

    const int tid = threadIdx.x;
    const int wid = tid >> 6, lane = tid & 63;
    const int lr = lane & 15, lg = lane >> 4;

    // register staging bases
    const int arow = tid >> 2, aquad = tid & 3;
    const float* abase = src + (size_t)(m0 + arow) * 1024 + aquad * 8;
    const int brow = tid >> 1, bhalf = tid & 1;
    const unsigned short* bhbase = BhT + (size_t)(n0 + brow) * 1024 + bhalf * 16;
    const unsigned short* blbase = BlT + (size_t)(n0 + brow) * 1024 + bhalf * 16;

    float4 av0, av1;
    uint4 bh0, bh1, bl0, bl1;

    auto load_tile = [&](int k0) {
        av0 = *(const float4*)(abase + k0);
        av1 = *(const float4*)(abase + k0 + 4);
        bh0 = *(const uint4*)(bhbase + k0);
        bh1 = *(const uint4*)(bhbase + k0 + 8);
        if (split) {
            bl0 = *(const uint4*)(blbase + k0);
            bl1 = *(const uint4*)(blbase + k0 + 8);
        }
    };
    auto write_tile = [&]() {
        float xs[8] = {av0.x, av0.y, av0.z, av0.w, av1.x, av1.y, av1.z, av1.w};
        __bf16 hs[8], ls[8];
        #pragma unroll
        for (int i = 0; i < 8; ++i) {
            __bf16 h = (__bf16)xs[i];    // RTNE, compiler pairs into v_cvt_pk_bf16_f32
            hs[i] = h;
            ls[i] = (__bf16)(xs[i] - (float)h);
        }
        *(uint4*)(Ah + arow * 40 + aquad * 8) = *(const uint4*)hs;
        if (split) *(uint4*)(Al + arow * 40 + aquad * 8) = *(const uint4*)ls;
        *(uint4*)(Bh + brow * 40 + bhalf * 16) = bh0;
        *(uint4*)(Bh + brow * 40 + bhalf * 16 + 8) = bh1;
        if (split) {
            *(uint4*)(Bl + brow * 40 + bhalf * 16) = bl0;
            *(uint4*)(Bl + brow * 40 + bhalf * 16 + 8) = bl1;
        }
    };

    f32x4 acc[8];
    #pragma unroll
    for (int t = 0; t < 8; ++t) acc[t] = f32x4{0.f, 0.f, 0.f, 0.f};

    load_tile(0);
    write_tile();
    __syncthreads();

    for (int ks = 0; ks < 32; ++ks) {
        if (ks < 31) load_tile((ks + 1) * 32);   // in flight under compute
        const bf16x8 a_h = *(const bf16x8*)(Ah + (wid * 16 + lr) * 40 + lg * 8);
        bf16x8 a_l;
        if (split) a_l = *(const bf16x8*)(Al + (wid * 16 + lr) * 40 + lg * 8);
        #pragma unroll
        for (int t = 0; t < 8; ++t) {
            const bf16x8 b_h = *(const bf16x8*)(Bh + (t * 16 + lr) * 40 + lg * 8);
            acc[t] = __builtin_amdgcn_mfma_f32_16x16x32_bf16(a_h, b_h, acc[t], 0, 0, 0);
            if (split) {
                const bf16x8 b_l = *(const bf16x8*)(Bl + (t * 16 + lr) * 40 + lg * 8);
                acc[t] = __builtin_amdgcn_mfma_f32_16x16x32_bf16(a_h, b_l, acc[t], 0, 0, 0);
                acc[t] = __builtin_amdgcn_mfma_f32_16x16x32_bf16(a_l, b_h, acc[t], 0, 0, 0);
            }
        }
        if (ks < 31) {
            __syncthreads();       // all fragment reads done
            write_tile();          // vmcnt waits land here
            __syncthreads();
        }
    }

    if (z < 2) {  // sign epilogue: +-1.0 bf16, flag near-zero for f64 fixup
        unsigned short* dst = (z == 0) ? Sq : Sk;
        const int whichbit = z << 22;
        #pragma unroll
        for (int t = 0; t < 8; ++t)
            #pragma unroll
            for (int j = 0; j < 4; ++j) {
                const int row = m0 + wid * 16 + 4 * lg + j;
                const int col = n0 + t * 16 + lr;
                const float zv = acc[t][j];
                dst[(size_t)row * 256 + col] =
                    (zv > 0.f) ? (unsigned short)0x3F80 : (unsigned short)0xBF80;
                if (__builtin_fabsf(zv) < FLAG_TAU) {
                    int slot = atomicAdd(flag_count, 1);
                    if (slot < FLAG_CAP) flags[slot] = whichbit | (row << 8) | col;
                }
            }
    } else {      // Vp -> VpT[b][h][key] bf16 via LDS transpose
        __syncthreads();
        unsigned short* tp = smem;  // [128][72]
        #pragma unroll
        for (int t = 0; t < 8; ++t)
            #pragma unroll
            for (int j = 0; j < 4; ++j) {
                const int h = t * 16 + lr;
                const int key = wid * 16 + 4 * lg + j;
                tp[h * 72 + key] = f2b(acc[t][j]);
            }
        __syncthreads();
        const int b = m0 >> 11, key0 = m0 & 2047;
        const int h = tid >> 1, half = tid & 1;
        const unsigned short* sp = tp + h * 72 + half * 32;
        unsigned short* gp = VpT + (size_t)(b * 128 + h) * 2048 + key0 + half * 32;
        #pragma unroll
        for (int i = 0; i < 4; ++i)
            *(uint4*)(gp + i * 8) = *(const uint4*)(sp + i * 8);
    }
}

// ---------------- f64 sign fixup of flagged borderline projections ----------------
__global__ __launch_bounds__(256) void fixup_kernel(
    const float* __restrict__ Q, const float* __restrict__ K,
    const float* __restrict__ Wq, const float* __restrict__ Wk,
    unsigned short* __restrict__ Sq, unsigned short* __restrict__ Sk,
    const int* __restrict__ flag_count, const int* __restrict__ flags)
{
    const int nflags = min(*flag_count, FLAG_CAP);
    const int wave = (int)(blockIdx.x * 256 + threadIdx.x) >> 6;
    const int lane = threadIdx.x & 63;
    const int nwaves = gridDim.x * 4;
    for (int i = wave; i < nflags; i += nwaves) {
        const int enc = flags[i];
        const int which = enc >> 22;
        const int row = (enc >> 8) & 0x3FFF;   // b*2048+n
        const int col = enc & 255;             // m
        const float* srow = (which ? K : Q) + (size_t)row * 1024;
        const float* W = (which ? Wk : Wq) + col;
        double accd = 0.0;
        #pragma unroll 4
        for (int d = lane; d < 1024; d += 64)
            accd += (double)srow[d] * (double)W[(size_t)d * 256];
        #pragma unroll
        for (int off = 32; off; off >>= 1) accd += __shfl_xor(accd, off);
        if (lane == 0)
            (which ? Sk : Sq)[(size_t)row * 256 + col] =
                (accd > 0.0) ? (unsigned short)0x3F80 : (unsigned short)0xBF80;
    }
}

// ---------------- attention (key-split x nsplit, adaptive) ----------------
// grid (32, 8, nsplit): 64 queries/block, 4 waves, 64/nsplit key-tiles of 32 per block.
// nsplit==1: writes normalized out directly. nsplit>1: writes f32 partials.
__global__ __launch_bounds__(256) void attn_kernel(
    const unsigned short* __restrict__ Sq, const unsigned short* __restrict__ Sk,
    const unsigned short* __restrict__ VpT,
    float* __restrict__ attn, float* __restrict__ out_or_part,
    float* __restrict__ rowsum_part, int nsplit)
{
    const int b = blockIdx.y;
    const int q0 = blockIdx.x * 64;
    const int sp = blockIdx.z;
    const int tid = threadIdx.x;
    const int wid = tid >> 6, lane = tid & 63;
    const int lr = lane & 15, lg = lane >> 4;

    __shared__ __align__(16) unsigned short sk_lds[32][264];
    __shared__ __align__(16) unsigned short vpt_lds[128][40];
    __shared__ __align__(16) unsigned short e_lds[4][16][40];

    uint4 sqf[8];  // wave-persistent sq fragments (q rows: wid*16+lr, all 256 mbits)
    {
        const unsigned short* p =
            Sq + (size_t)(b * 2048 + q0 + wid * 16 + lr) * 256 + lg * 8;
        #pragma unroll
        for (int s = 0; s < 8; ++s) sqf[s] = *(const uint4*)(p + s * 32);
    }

    f32x4 oacc[8];
    #pragma unroll
    for (int t = 0; t < 8; ++t) oacc[t] = f32x4{0.f, 0.f, 0.f, 0.f};
    float racc[4] = {0.f, 0.f, 0.f, 0.f};

    float* attn_row_base = attn + (size_t)(b * 2048 + q0 + wid * 16 + 4 * lg) * 2048;

    const int tiles = 64 / nsplit;
    for (int kt = sp * tiles; kt < sp * tiles + tiles; ++kt) {
        const int kt0 = kt * 32;
        __syncthreads();
        {   // stage sk: 32 keys x 256 mbits
            const int row = tid >> 3, chunk = tid & 7;
            const unsigned short* p = Sk + (size_t)(b * 2048 + kt0 + row) * 256 + chunk * 32;
            uint4 v0 = *(const uint4*)(p);
            uint4 v1 = *(const uint4*)(p + 8);
            uint4 v2 = *(const uint4*)(p + 16);
            uint4 v3 = *(const uint4*)(p + 24);
            unsigned short* q = &sk_lds[row][chunk * 32];
            *(uint4*)(q) = v0; *(uint4*)(q + 8) = v1;
            *(uint4*)(q + 16) = v2; *(uint4*)(q + 24) = v3;
        }
        {   // stage VpT: 128 h x 32 keys
            const int h = tid >> 1, half = tid & 1;
            const unsigned short* p = VpT + (size_t)(b * 128 + h) * 2048 + kt0 + half * 16;
            uint4 v0 = *(const uint4*)(p);
            uint4 v1 = *(const uint4*)(p + 8);
            unsigned short* q = &vpt_lds[h][half * 16];
            *(uint4*)(q) = v0; *(uint4*)(q + 8) = v1;
        }
        __syncthreads();

        // exact score MFMA: dot[q 16][key 32]
        f32x4 dacc[2];
        dacc[0] = f32x4{0.f, 0.f, 0.f, 0.f};
        dacc[1] = f32x4{0.f, 0.f, 0.f, 0.f};
        #pragma unroll
        for (int s = 0; s < 8; ++s) {
            const bf16x8 a = *(const bf16x8*)(&sqf[s]);
            #pragma unroll
            for (int t2 = 0; t2 < 2; ++t2) {
                const bf16x8 bk = *(const bf16x8*)(&sk_lds[t2 * 16 + lr][s * 32 + lg * 8]);
                dacc[t2] = __builtin_amdgcn_mfma_f32_16x16x32_bf16(a, bk, dacc[t2], 0, 0, 0);
            }
        }
        // e = exp(score) (no max needed: score <= 16), store unnormalized, stage for PV
        #pragma unroll
        for (int t2 = 0; t2 < 2; ++t2)
            #pragma unroll
            for (int j = 0; j < 4; ++j) {
                float e = __expf((dacc[t2][j] + 256.0f) * 0.03125f);
                racc[j] += e;
                attn_row_base[(size_t)j * 2048 + kt0 + t2 * 16 + lr] = e;
                e_lds[wid][4 * lg + j][t2 * 16 + lr] = f2b(e);
            }
        // PV MFMA: out[q 16][h 128] += e[q][key 32] * Vp[key][h]
        const bf16x8 ea = *(const bf16x8*)(&e_lds[wid][lr][lg * 8]);
        #pragma unroll
        for (int t = 0; t < 8; ++t) {
            const bf16x8 vb = *(const bf16x8*)(&vpt_lds[t * 16 + lr][lg * 8]);
            oacc[t] = __builtin_amdgcn_mfma_f32_16x16x32_bf16(ea, vb, oacc[t], 0, 0, 0);
        }
    }

    // partial rowsum: reduce over the 16 lanes of each lane-group
    #pragma unroll
    for (int j = 0; j < 4; ++j) {
        float v = racc[j];
        v += __shfl_xor(v, 1);
        v += __shfl_xor(v, 2);
        v += __shfl_xor(v, 4);
        v += __shfl_xor(v, 8);
        racc[j] = v;
    }
    if (lr == 0) {
        #pragma unroll
        for (int j = 0; j < 4; ++j)
            rowsum_part[sp * 16384 + b * 2048 + q0 + wid * 16 + 4 * lg + j] = racc[j];
    }
    if (nsplit == 1) {
        #pragma unroll
        for (int t = 0; t < 8; ++t)
            #pragma unroll
            for (int j = 0; j < 4; ++j)
                out_or_part[(size_t)(b * 2048 + q0 + wid * 16 + 4 * lg + j) * 128
                            + t * 16 + lr] = oacc[t][j] / racc[j];
    } else {
        #pragma unroll
        for (int t = 0; t < 8; ++t)
            #pragma unroll
            for (int j = 0; j < 4; ++j)
                out_or_part[((size_t)sp * 16384 + b * 2048 + q0 + wid * 16 + 4 * lg + j) * 128
                            + t * 16 + lr] = oacc[t][j];
    }
}

// ---------------- out finalize: sum partials, divide by rowsum (nsplit>1) ----------------
__global__ __launch_bounds__(256) void out_finalize(
    float* __restrict__ out, const float* __restrict__ out_part,
    const float* __restrict__ rowsum_part, int nsplit)
{
    const int idx4 = blockIdx.x * 256 + threadIdx.x;   // [0, 524288) float4 over out
    const int row = idx4 >> 5;                          // 32 float4 per 128-col row
    float rs = 0.f;
    for (int k = 0; k < nsplit; ++k) rs += rowsum_part[k * 16384 + row];
    float4 s = {0.f, 0.f, 0.f, 0.f};
    const float4* p = (const float4*)out_part;
    for (int k = 0; k < nsplit; ++k) {
        float4 v = p[(size_t)k * 524288 + idx4];
        s.x += v.x; s.y += v.y; s.z += v.z; s.w += v.w;
    }
    const float inv = 1.0f / rs;
    float4 r = {s.x * inv, s.y * inv, s.z * inv, s.w * inv};
    ((float4*)out)[idx4] = r;
}

// ---------------- attn normalization ----------------
__global__ __launch_bounds__(256) void normalize_kernel(
    float* __restrict__ attn, const float* __restrict__ rowsum_part, int nsplit)
{
    const size_t idx4 = (size_t)blockIdx.x * 256 + threadIdx.x;  // float4 index
    const int row = (int)(idx4 >> 9);                            // 512 float4 per row
    float rs = 0.f;
    for (int k = 0; k < nsplit; ++k) rs += rowsum_part[k * 16384 + row];
    const float inv = 1.0f / rs;
    float4* p = (float4*)attn + idx4;
    float4 v = *p;
    v.x *= inv; v.y *= inv; v.z *= inv; v.w *= inv;
    *p = v;
}

extern "C" void kernel_launch(void* const* d_in, const int* in_sizes, int n_in,
                              void* d_out, int out_size, void* d_ws, size_t ws_size,
                              hipStream_t stream)
{
    const float* Q  = (const float*)d_in[0];
    const float* K  = (const float*)d_in[1];
    const float* V  = (const float*)d_in[2];
    const float* Wq = (const float*)d_in[3];
    const float* Wk = (const float*)d_in[4];
    const float* Wv = (const float*)d_in[5];

    unsigned short* ws   = (unsigned short*)d_ws;
    unsigned short* WqhT = ws;
    unsigned short* WqlT = WqhT + 262144;
    unsigned short* WkhT = WqlT + 262144;
    unsigned short* WklT = WkhT + 262144;
    unsigned short* WvhT = WklT + 262144;
    unsigned short* Sq   = WvhT + 131072;
    unsigned short* Sk   = Sq + 4194304;
    unsigned short* VpT  = Sk + 4194304;
    int* flag_count    = (int*)(VpT + 2097152);
    int* flags         = flag_count + 1;
    float* rowsum_part = (float*)(flags + FLAG_CAP);   // [nsplit][16384]
    // fixed part ends at rowsum_part; bytes used so far:
    const size_t fixed_bytes = (size_t)((char*)rowsum_part - (char*)d_ws);

    // choose nsplit by available workspace (constant across calls -> graph-safe)
    int nsplit = 1;
    if (ws_size >= fixed_bytes + 4u * (16384u + 2097152u) * sizeof(float)) nsplit = 4;
    else if (ws_size >= fixed_bytes + 2u * (16384u + 2097152u) * sizeof(float)) nsplit = 2;

    float* out_part = rowsum_part + (size_t)nsplit * 16384;  // [nsplit][16384][128] if nsplit>1

    float* out  = (float*)d_out;
    float* attn = out + 2097152;  // 8*2048*128

    prep_weights<<<2560, 256, 0, stream>>>(Wq, Wk, Wv, WqhT, WqlT, WkhT, WklT, WvhT,
                                           flag_count);
    proj_kernel<<<dim3(256, 2, 3), 256, 0, stream>>>(Q, K, V, WqhT, WqlT, WkhT, WklT, WvhT,
                                                     Sq, Sk, VpT, flag_count, flags);
    fixup_kernel<<<64, 256, 0, stream>>>(Q, K, Wq, Wk, Sq, Sk, flag_count, flags);
    attn_kernel<<<dim3(32, 8, nsplit), 256, 0, stream>>>(
        Sq, Sk, VpT, attn, (nsplit == 1) ? out : out_part, rowsum_part, nsplit);
    if (nsplit > 1)
        out_finalize<<<2048, 256, 0, stream>>>(out, out_part, rowsum_part, nsplit);
    normalize_kernel<<<32768, 256, 0, stream>>>(attn, rowsum_part, nsplit);
}

// Round 12
// 480.629 us; speedup vs baseline: 1.1501x; 1.0040x over previous
//
#include <hip/hip_runtime.h>

// BooleanREWAHead on MI355X (gfx950). R11: proj merged-y (BN=256: one block
// does all 256 weight cols -> A loaded+split ONCE, 48 MFMA/barrier/wave).
// attn key-split x{4,2,1} adaptive to ws_size (unchanged from R9).
// ws layout (fixed part ~22.4 MB): WqhT,WqlT,WkhT,WklT [256][1024]bf16,
// WvhT [128][1024]bf16, Sq,Sk [16384][256]bf16, VpT [8*128][2048]bf16,
// flag_count i32, flags[32768] i32, then rowsum_part [ns][16384]f32,
// out_part [ns][16384][128]f32 (only if ns>1).

typedef __attribute__((ext_vector_type(4))) float f32x4;
typedef __attribute__((ext_vector_type(8))) __bf16 bf16x8;

#define FLAG_CAP 32768
#define FLAG_TAU 2e-4f   // 50 sigma of 3-pass split error (sigma ~4e-6)

__device__ inline unsigned short f2b(float x) {  // f32 -> bf16 bits, RTNE
    unsigned int u = __float_as_uint(x);
    return (unsigned short)((u + 0x7FFFu + ((u >> 16) & 1u)) >> 16);
}

// ---------------- weight split+transpose ----------------
__global__ __launch_bounds__(256) void prep_weights(
    const float* __restrict__ Wq, const float* __restrict__ Wk, const float* __restrict__ Wv,
    unsigned short* __restrict__ WqhT, unsigned short* __restrict__ WqlT,
    unsigned short* __restrict__ WkhT, unsigned short* __restrict__ WklT,
    unsigned short* __restrict__ WvhT, int* __restrict__ flag_count)
{
    if (blockIdx.x == 0 && threadIdx.x == 0) *flag_count = 0;  // visible to next kernel
    int i = blockIdx.x * 256 + threadIdx.x;  // [0, 655360)
    const float* src; unsigned short *dh, *dl; int cols, j;
    if (i < 262144)      { src = Wq; dh = WqhT; dl = WqlT; cols = 256; j = i; }
    else if (i < 524288) { src = Wk; dh = WkhT; dl = WklT; cols = 256; j = i - 262144; }
    else                 { src = Wv; dh = WvhT; dl = nullptr; cols = 128; j = i - 524288; }
    int d = j / cols, m = j % cols;
    float x = src[j];
    unsigned short h = f2b(x);
    dh[(size_t)m * 1024 + d] = h;
    if (dl) {
        float hf = __uint_as_float(((unsigned int)h) << 16);
        dl[(size_t)m * 1024 + d] = f2b(x - hf);
    }
}

// ---------------- projection GEMM (2-phase reg-staged, merged BN=256) ----------------
// grid (256, 3): z=0 Q->Sq, z=1 K->Sk (3-pass split, all 256 cols), z=2 V->VpT (128 cols)
__global__ __launch_bounds__(256, 3) void proj_kernel(
    const float* __restrict__ Q, const float* __restrict__ K, const float* __restrict__ V,
    const unsigned short* __restrict__ WqhT, const unsigned short* __restrict__ WqlT,
    const unsigned short* __restrict__ WkhT, const unsigned short* __restrict__ WklT,
    const unsigned short* __restrict__ WvhT,
    unsigned short* __restrict__ Sq, unsigned short* __restrict__ Sk,
    unsigned short* __restrict__ VpT,
    int* __restrict__ flag_count, int* __restrict__ flags)
{
    const int z = blockIdx.y;
    const int m0 = blockIdx.x * 64;
    const bool split = (z < 2);
    const float* src = (z == 0) ? Q : (z == 1) ? K : V;
    const unsigned short* BhT = (z == 0) ? WqhT : (z == 1) ? WkhT : WvhT;
    const unsigned short* BlT = (z == 0) ? WqlT : WklT;

    __shared__ __align__(16) unsigned short smem[25600];  // 51.2 KB
    unsigned short* Ah = smem;           // [64][40]
    unsigned short* Al = smem + 2560;    // [64][40]
    unsigned short* Bh = smem + 5120;    // [256][40]
    unsigned short* Bl = smem + 15360;   // [256][40]

    const int tid = threadIdx.x;
    const int wid = tid >> 6, lane = tid & 63;
    const int lr = lane & 15, lg = lane >> 4;

    // register staging bases
    const int arow = tid >> 2, aquad = tid & 3;
    const float* abase = src + (size_t)(m0 + arow) * 1024 + aquad * 8;
    const int brow = tid;                       // one weight row per thread
    const bool bvalid = split || (tid < 128);   // Wv has only 128 rows
    const unsigned short* bhbase = BhT + (size_t)brow * 1024;
    const unsigned short* blbase = BlT + (size_t)brow * 1024;

    float4 av0, av1;
    uint4 bh0, bh1, bh2, bh3, bl0, bl1, bl2, bl3;

    auto load_tile = [&](int k0) {
        av0 = *(const float4*)(abase + k0);
        av1 = *(const float4*)(abase + k0 + 4);
        if (bvalid) {
            bh0 = *(const uint4*)(bhbase + k0);
            bh1 = *(const uint4*)(bhbase + k0 + 8);
            bh2 = *(const uint4*)(bhbase + k0 + 16);
            bh3 = *(const uint4*)(bhbase + k0 + 24);
            if (split) {
                bl0 = *(const uint4*)(blbase + k0);
                bl1 = *(const uint4*)(blbase + k0 + 8);
                bl2 = *(const uint4*)(blbase + k0 + 16);
                bl3 = *(const uint4*)(blbase + k0 + 24);
            }
        }
    };
    auto write_tile = [&]() {
        float xs[8] = {av0.x, av0.y, av0.z, av0.w, av1.x, av1.y, av1.z, av1.w};
        __bf16 hs[8], ls[8];
        #pragma unroll
        for (int i = 0; i < 8; ++i) {
            __bf16 h = (__bf16)xs[i];    // RTNE, pairs into v_cvt_pk_bf16_f32
            hs[i] = h;
            ls[i] = (__bf16)(xs[i] - (float)h);
        }
        *(uint4*)(Ah + arow * 40 + aquad * 8) = *(const uint4*)hs;
        if (split) *(uint4*)(Al + arow * 40 + aquad * 8) = *(const uint4*)ls;
        if (bvalid) {
            *(uint4*)(Bh + brow * 40)      = bh0;
            *(uint4*)(Bh + brow * 40 + 8)  = bh1;
            *(uint4*)(Bh + brow * 40 + 16) = bh2;
            *(uint4*)(Bh + brow * 40 + 24) = bh3;
            if (split) {
                *(uint4*)(Bl + brow * 40)      = bl0;
                *(uint4*)(Bl + brow * 40 + 8)  = bl1;
                *(uint4*)(Bl + brow * 40 + 16) = bl2;
                *(uint4*)(Bl + brow * 40 + 24) = bl3;
            }
        }
    };

    f32x4 acc[16];
    #pragma unroll
    for (int t = 0; t < 16; ++t) acc[t] = f32x4{0.f, 0.f, 0.f, 0.f};

    load_tile(0);
    write_tile();
    __syncthreads();

    for (int ks = 0; ks < 32; ++ks) {
        if (ks < 31) load_tile((ks + 1) * 32);   // in flight under compute
        const bf16x8 a_h = *(const bf16x8*)(Ah + (wid * 16 + lr) * 40 + lg * 8);
        if (split) {
            const bf16x8 a_l = *(const bf16x8*)(Al + (wid * 16 + lr) * 40 + lg * 8);
            #pragma unroll
            for (int t = 0; t < 16; ++t) {
                const bf16x8 b_h = *(const bf16x8*)(Bh + (t * 16 + lr) * 40 + lg * 8);
                const bf16x8 b_l = *(const bf16x8*)(Bl + (t * 16 + lr) * 40 + lg * 8);
                acc[t] = __builtin_amdgcn_mfma_f32_16x16x32_bf16(a_h, b_h, acc[t], 0, 0, 0);
                acc[t] = __builtin_amdgcn_mfma_f32_16x16x32_bf16(a_h, b_l, acc[t], 0, 0, 0);
                acc[t] = __builtin_amdgcn_mfma_f32_16x16x32_bf16(a_l, b_h, acc[t], 0, 0, 0);
            }
        } else {
            #pragma unroll
            for (int t = 0; t < 8; ++t) {
                const bf16x8 b_h = *(const bf16x8*)(Bh + (t * 16 + lr) * 40 + lg * 8);
                acc[t] = __builtin_amdgcn_mfma_f32_16x16x32_bf16(a_h, b_h, acc[t], 0, 0, 0);
            }
        }
        if (ks < 31) {
            __syncthreads();       // all fragment reads done
            write_tile();          // vmcnt waits land here
            __syncthreads();
        }
    }

    if (split) {  // sign epilogue: +-1.0 bf16, flag near-zero for f64 fixup
        unsigned short* dst = (z == 0) ? Sq : Sk;
        const int whichbit = z << 22;
        #pragma unroll
        for (int t = 0; t < 16; ++t)
            #pragma unroll
            for (int j = 0; j < 4; ++j) {
                const int row = m0 + wid * 16 + 4 * lg + j;
                const int col = t * 16 + lr;
                const float zv = acc[t][j];
                dst[(size_t)row * 256 + col] =
                    (zv > 0.f) ? (unsigned short)0x3F80 : (unsigned short)0xBF80;
                if (__builtin_fabsf(zv) < FLAG_TAU) {
                    int slot = atomicAdd(flag_count, 1);
                    if (slot < FLAG_CAP) flags[slot] = whichbit | (row << 8) | col;
                }
            }
    } else {      // Vp -> VpT[b][h][key] bf16 via LDS transpose
        __syncthreads();
        unsigned short* tp = smem;  // [128][72]
        #pragma unroll
        for (int t = 0; t < 8; ++t)
            #pragma unroll
            for (int j = 0; j < 4; ++j) {
                const int h = t * 16 + lr;
                const int key = wid * 16 + 4 * lg + j;
                tp[h * 72 + key] = f2b(acc[t][j]);
            }
        __syncthreads();
        const int b = m0 >> 11, key0 = m0 & 2047;
        const int h = tid >> 1, half = tid & 1;
        const unsigned short* sp = tp + h * 72 + half * 32;
        unsigned short* gp = VpT + (size_t)(b * 128 + h) * 2048 + key0 + half * 32;
        #pragma unroll
        for (int i = 0; i < 4; ++i)
            *(uint4*)(gp + i * 8) = *(const uint4*)(sp + i * 8);
    }
}

// ---------------- f64 sign fixup of flagged borderline projections ----------------
__global__ __launch_bounds__(256) void fixup_kernel(
    const float* __restrict__ Q, const float* __restrict__ K,
    const float* __restrict__ Wq, const float* __restrict__ Wk,
    unsigned short* __restrict__ Sq, unsigned short* __restrict__ Sk,
    const int* __restrict__ flag_count, const int* __restrict__ flags)
{
    const int nflags = min(*flag_count, FLAG_CAP);
    const int wave = (int)(blockIdx.x * 256 + threadIdx.x) >> 6;
    const int lane = threadIdx.x & 63;
    const int nwaves = gridDim.x * 4;
    for (int i = wave; i < nflags; i += nwaves) {
        const int enc = flags[i];
        const int which = enc >> 22;
        const int row = (enc >> 8) & 0x3FFF;   // b*2048+n
        const int col = enc & 255;             // m
        const float* srow = (which ? K : Q) + (size_t)row * 1024;
        const float* W = (which ? Wk : Wq) + col;
        double accd = 0.0;
        #pragma unroll 4
        for (int d = lane; d < 1024; d += 64)
            accd += (double)srow[d] * (double)W[(size_t)d * 256];
        #pragma unroll
        for (int off = 32; off; off >>= 1) accd += __shfl_xor(accd, off);
        if (lane == 0)
            (which ? Sk : Sq)[(size_t)row * 256 + col] =
                (accd > 0.0) ? (unsigned short)0x3F80 : (unsigned short)0xBF80;
    }
}

// ---------------- attention (key-split x nsplit, adaptive) ----------------
// grid (32, 8, nsplit): 64 queries/block, 4 waves, 64/nsplit key-tiles of 32 per block.
// nsplit==1: writes normalized out directly. nsplit>1: writes f32 partials.
__global__ __launch_bounds__(256) void attn_kernel(
    const unsigned short* __restrict__ Sq, const unsigned short* __restrict__ Sk,
    const unsigned short* __restrict__ VpT,
    float* __restrict__ attn, float* __restrict__ out_or_part,
    float* __restrict__ rowsum_part, int nsplit)
{
    const int b = blockIdx.y;
    const int q0 = blockIdx.x * 64;
    const int sp = blockIdx.z;
    const int tid = threadIdx.x;
    const int wid = tid >> 6, lane = tid & 63;
    const int lr = lane & 15, lg = lane >> 4;

    __shared__ __align__(16) unsigned short sk_lds[32][264];
    __shared__ __align__(16) unsigned short vpt_lds[128][40];
    __shared__ __align__(16) unsigned short e_lds[4][16][40];

    uint4 sqf[8];  // wave-persistent sq fragments (q rows: wid*16+lr, all 256 mbits)
    {
        const unsigned short* p =
            Sq + (size_t)(b * 2048 + q0 + wid * 16 + lr) * 256 + lg * 8;
        #pragma unroll
        for (int s = 0; s < 8; ++s) sqf[s] = *(const uint4*)(p + s * 32);
    }

    f32x4 oacc[8];
    #pragma unroll
    for (int t = 0; t < 8; ++t) oacc[t] = f32x4{0.f, 0.f, 0.f, 0.f};
    float racc[4] = {0.f, 0.f, 0.f, 0.f};

    float* attn_row_base = attn + (size_t)(b * 2048 + q0 + wid * 16 + 4 * lg) * 2048;

    const int tiles = 64 / nsplit;
    for (int kt = sp * tiles; kt < sp * tiles + tiles; ++kt) {
        const int kt0 = kt * 32;
        __syncthreads();
        {   // stage sk: 32 keys x 256 mbits
            const int row = tid >> 3, chunk = tid & 7;
            const unsigned short* p = Sk + (size_t)(b * 2048 + kt0 + row) * 256 + chunk * 32;
            uint4 v0 = *(const uint4*)(p);
            uint4 v1 = *(const uint4*)(p + 8);
            uint4 v2 = *(const uint4*)(p + 16);
            uint4 v3 = *(const uint4*)(p + 24);
            unsigned short* q = &sk_lds[row][chunk * 32];
            *(uint4*)(q) = v0; *(uint4*)(q + 8) = v1;
            *(uint4*)(q + 16) = v2; *(uint4*)(q + 24) = v3;
        }
        {   // stage VpT: 128 h x 32 keys
            const int h = tid >> 1, half = tid & 1;
            const unsigned short* p = VpT + (size_t)(b * 128 + h) * 2048 + kt0 + half * 16;
            uint4 v0 = *(const uint4*)(p);
            uint4 v1 = *(const uint4*)(p + 8);
            unsigned short* q = &vpt_lds[h][half * 16];
            *(uint4*)(q) = v0; *(uint4*)(q + 8) = v1;
        }
        __syncthreads();

        // exact score MFMA: dot[q 16][key 32]
        f32x4 dacc[2];
        dacc[0] = f32x4{0.f, 0.f, 0.f, 0.f};
        dacc[1] = f32x4{0.f, 0.f, 0.f, 0.f};
        #pragma unroll
        for (int s = 0; s < 8; ++s) {
            const bf16x8 a = *(const bf16x8*)(&sqf[s]);
            #pragma unroll
            for (int t2 = 0; t2 < 2; ++t2) {
                const bf16x8 bk = *(const bf16x8*)(&sk_lds[t2 * 16 + lr][s * 32 + lg * 8]);
                dacc[t2] = __builtin_amdgcn_mfma_f32_16x16x32_bf16(a, bk, dacc[t2], 0, 0, 0);
            }
        }
        // e = exp(score) (no max needed: score <= 16), store unnormalized, stage for PV
        #pragma unroll
        for (int t2 = 0; t2 < 2; ++t2)
            #pragma unroll
            for (int j = 0; j < 4; ++j) {
                float e = __expf((dacc[t2][j] + 256.0f) * 0.03125f);
                racc[j] += e;
                attn_row_base[(size_t)j * 2048 + kt0 + t2 * 16 + lr] = e;
                e_lds[wid][4 * lg + j][t2 * 16 + lr] = f2b(e);
            }
        // PV MFMA: out[q 16][h 128] += e[q][key 32] * Vp[key][h]
        const bf16x8 ea = *(const bf16x8*)(&e_lds[wid][lr][lg * 8]);
        #pragma unroll
        for (int t = 0; t < 8; ++t) {
            const bf16x8 vb = *(const bf16x8*)(&vpt_lds[t * 16 + lr][lg * 8]);
            oacc[t] = __builtin_amdgcn_mfma_f32_16x16x32_bf16(ea, vb, oacc[t], 0, 0, 0);
        }
    }

    // partial rowsum: reduce over the 16 lanes of each lane-group
    #pragma unroll
    for (int j = 0; j < 4; ++j) {
        float v = racc[j];
        v += __shfl_xor(v, 1);
        v += __shfl_xor(v, 2);
        v += __shfl_xor(v, 4);
        v += __shfl_xor(v, 8);
        racc[j] = v;
    }
    if (lr == 0) {
        #pragma unroll
        for (int j = 0; j < 4; ++j)
            rowsum_part[sp * 16384 + b * 2048 + q0 + wid * 16 + 4 * lg + j] = racc[j];
    }
    if (nsplit == 1) {
        #pragma unroll
        for (int t = 0; t < 8; ++t)
            #pragma unroll
            for (int j = 0; j < 4; ++j)
                out_or_part[(size_t)(b * 2048 + q0 + wid * 16 + 4 * lg + j) * 128
                            + t * 16 + lr] = oacc[t][j] / racc[j];
    } else {
        #pragma unroll
        for (int t = 0; t < 8; ++t)
            #pragma unroll
            for (int j = 0; j < 4; ++j)
                out_or_part[((size_t)sp * 16384 + b * 2048 + q0 + wid * 16 + 4 * lg + j) * 128
                            + t * 16 + lr] = oacc[t][j];
    }
}

// ---------------- out finalize: sum partials, divide by rowsum (nsplit>1) ----------------
__global__ __launch_bounds__(256) void out_finalize(
    float* __restrict__ out, const float* __restrict__ out_part,
    const float* __restrict__ rowsum_part, int nsplit)
{
    const int idx4 = blockIdx.x * 256 + threadIdx.x;   // [0, 524288) float4 over out
    const int row = idx4 >> 5;                          // 32 float4 per 128-col row
    float rs = 0.f;
    for (int k = 0; k < nsplit; ++k) rs += rowsum_part[k * 16384 + row];
    float4 s = {0.f, 0.f, 0.f, 0.f};
    const float4* p = (const float4*)out_part;
    for (int k = 0; k < nsplit; ++k) {
        float4 v = p[(size_t)k * 524288 + idx4];
        s.x += v.x; s.y += v.y; s.z += v.z; s.w += v.w;
    }
    const float inv = 1.0f / rs;
    float4 r = {s.x * inv, s.y * inv, s.z * inv, s.w * inv};
    ((float4*)out)[idx4] = r;
}

// ---------------- attn normalization ----------------
__global__ __launch_bounds__(256) void normalize_kernel(
    float* __restrict__ attn, const float* __restrict__ rowsum_part, int nsplit)
{
    const size_t idx4 = (size_t)blockIdx.x * 256 + threadIdx.x;  // float4 index
    const int row = (int)(idx4 >> 9);                            // 512 float4 per row
    float rs = 0.f;
    for (int k = 0; k < nsplit; ++k) rs += rowsum_part[k * 16384 + row];
    const float inv = 1.0f / rs;
    float4* p = (float4*)attn + idx4;
    float4 v = *p;
    v.x *= inv; v.y *= inv; v.z *= inv; v.w *= inv;
    *p = v;
}

extern "C" void kernel_launch(void* const* d_in, const int* in_sizes, int n_in,
                              void* d_out, int out_size, void* d_ws, size_t ws_size,
                              hipStream_t stream)
{
    const float* Q  = (const float*)d_in[0];
    const float* K  = (const float*)d_in[1];
    const float* V  = (const float*)d_in[2];
    const float* Wq = (const float*)d_in[3];
    const float* Wk = (const float*)d_in[4];
    const float* Wv = (const float*)d_in[5];

    unsigned short* ws   = (unsigned short*)d_ws;
    unsigned short* WqhT = ws;
    unsigned short* WqlT = WqhT + 262144;
    unsigned short* WkhT = WqlT + 262144;
    unsigned short* WklT = WkhT + 262144;
    unsigned short* WvhT = WklT + 262144;
    unsigned short* Sq   = WvhT + 131072;
    unsigned short* Sk   = Sq + 4194304;
    unsigned short* VpT  = Sk + 4194304;
    int* flag_count    = (int*)(VpT + 2097152);
    int* flags         = flag_count + 1;
    float* rowsum_part = (float*)(flags + FLAG_CAP);   // [nsplit][16384]
    // fixed part ends at rowsum_part; bytes used so far:
    const size_t fixed_bytes = (size_t)((char*)rowsum_part - (char*)d_ws);

    // choose nsplit by available workspace (constant across calls -> graph-safe)
    int nsplit = 1;
    if (ws_size >= fixed_bytes + 4u * (16384u + 2097152u) * sizeof(float)) nsplit = 4;
    else if (ws_size >= fixed_bytes + 2u * (16384u + 2097152u) * sizeof(float)) nsplit = 2;

    float* out_part = rowsum_part + (size_t)nsplit * 16384;  // [nsplit][16384][128] if nsplit>1

    float* out  = (float*)d_out;
    float* attn = out + 2097152;  // 8*2048*128

    prep_weights<<<2560, 256, 0, stream>>>(Wq, Wk, Wv, WqhT, WqlT, WkhT, WklT, WvhT,
                                           flag_count);
    proj_kernel<<<dim3(256, 3), 256, 0, stream>>>(Q, K, V, WqhT, WqlT, WkhT, WklT, WvhT,
                                                  Sq, Sk, VpT, flag_count, flags);
    fixup_kernel<<<64, 256, 0, stream>>>(Q, K, Wq, Wk, Sq, Sk, flag_count, flags);
    attn_kernel<<<dim3(32, 8, nsplit), 256, 0, stream>>>(
        Sq, Sk, VpT, attn, (nsplit == 1) ? out : out_part, rowsum_part, nsplit);
    if (nsplit > 1)
        out_finalize<<<2048, 256, 0, stream>>>(out, out_part, rowsum_part, nsplit);
    normalize_kernel<<<32768, 256, 0, stream>>>(attn, rowsum_part, nsplit);
}